// Round 5
// baseline (220.395 us; speedup 1.0000x reference)
//
#include <hip/hip_runtime.h>

typedef float  f32x4  __attribute__((ext_vector_type(4)));
typedef float  f32x2  __attribute__((ext_vector_type(2)));
typedef short  bf16x8 __attribute__((ext_vector_type(8)));

#define TWOLOG2E   2.8853900817779268f
#define NLOG2E    -1.4426950408889634f
#define NTWOLOG2E -2.8853900817779268f

__device__ __forceinline__ unsigned short f2b(float f) {      // fp32 -> bf16 RNE
    unsigned int u = __builtin_bit_cast(unsigned int, f);
    u += 0x7fffu + ((u >> 16) & 1u);
    return (unsigned short)(u >> 16);
}
__device__ __forceinline__ float b2f(unsigned short s) {
    unsigned int u = ((unsigned int)s) << 16;
    return __builtin_bit_cast(float, u);
}
__device__ __forceinline__ unsigned int pk2(float lo, float hi) {
#if __has_builtin(__builtin_amdgcn_cvt_pk_bf16_f32)
    typedef __bf16 bf16x2 __attribute__((ext_vector_type(2)));
    bf16x2 p = __builtin_amdgcn_cvt_pk_bf16_f32(lo, hi);
    return __builtin_bit_cast(unsigned int, p);
#else
    return (unsigned int)f2b(lo) | ((unsigned int)f2b(hi) << 16);
#endif
}
__device__ __forceinline__ float frcp(float x) { return __builtin_amdgcn_rcpf(x); }
__device__ __forceinline__ float fex2(float x) { return __builtin_amdgcn_exp2f(x); }

// R18: transposed GEMM orientation — gates^T = W·h^T (W = A operand, h = B).
// With RowMap(g,w): unit=8*(w>>2)+2*(g&3)+(w&1), gate=2*(g>>2)+((w>>1)&1),
// lane (q,m)'s D values are the 4 gates x 8 units (8q..8q+7) of batch m, and
// the epilogue's 4 pk2 words ARE the next MFMA's B-frag (B[k=unit][n=batch]:
// lane(n=m,q) holds units q*8+j). So:
//   - recurrence (t->t+1) lives entirely in registers (no LDS round-trip;
//     this was the ~2x150-300cyc serial latency per superstep = the idle)
//   - cross-layer handoff = layout-preserving linear 16B/lane LDS write/read
//     (1 ds_write_b128 + 1 ds_read_b128 per 16-batch tile, conflict-free)
//   - hb zero-init eliminated (first cross-layer read is producer-written)
// Same pipeline as R9/R14: 32 rows/block, grid 512, 2 blocks/CU = 2 waves/SIMD
// (R15: 4 waves spills), wave l owns layer l, 2-timestep supersteps, 35
// barriers, weights pre-scaled by -log2e (-2log2e for g-gate), bias in MFMA C
// (cbq, now per-row values via RowMap). Epilogue (packed f32x2 over unit
// pairs, 5 exp2 + 2 rcp per unit — instruction floor per R14/R16/R17):
//   p1=(1+ei)(1+eg); cn' = [cp*p1 - 2log2e(1-eg)(1+ef)] * rcp(p1*(1+ef))
//   (cp = -2log2e*c);  ec = exp2(cp);  h = (1-ec)*rcp((1+eo)(1+ec))
__global__ __launch_bounds__(256, 2)
void lstm_mfma(const float* __restrict__ xg,  const float* __restrict__ Wih0,
               const float* __restrict__ Wih, const float* __restrict__ Whh,
               const float* __restrict__ bih, const float* __restrict__ bhh,
               const float* __restrict__ Wlin,const float* __restrict__ blin,
               float* __restrict__ out) {
    // hb: [l][parity][slot01] x (tt*256 + lane*4 + w) u32  = 16 slots x 2KB
    __shared__ unsigned int hb[16 * 512] __attribute__((aligned(16)));
    __shared__ unsigned int xb[64 * 32];                    // [t][row] 2xbf16

    const int tid  = threadIdx.x;
    const int wv   = __builtin_amdgcn_readfirstlane(tid >> 6);  // layer id, uniform
    const int lane = tid & 63;
    const int m    = lane & 15;    // batch index within 16-tile (B col / D col)
    const int q    = lane >> 4;    // quad: unit octet 8q..8q+7, k-chunk q*8..
    const int row0 = blockIdx.x * 32;

    // stage x -> LDS bf16 [t][row]
    for (int i = tid; i < 2048; i += 256) {
        int r = i >> 6, t = i & 63;
        float x0 = xg[(size_t)(row0 + r) * 192 + t];
        float x1 = xg[(size_t)(row0 + r) * 192 + 64 + t];
        xb[t * 32 + r] = pk2(x0, x1);
    }

    // ---- one-time gather of A-frags (weights) + bias quads ----
    // A-frag lane (m,q): A[row m][k q*8+j] = W[RowMap(g,m)][k], scaled.
    bf16x8 afr[2][8];   // [src: 0=input (Wih), 1=recurrent (Whh)][g]
    f32x4  cbq[8];      // bias C quads: element r = row q*4+r = RowMap(g,q*4+r)
#pragma unroll
    for (int g = 0; g < 8; ++g) {
        const int   u_m  = 8 * (m >> 2) + 2 * (g & 3) + (m & 1);
        const int   gt_m = 2 * (g >> 2) + ((m >> 1) & 1);
        const int   rowG = gt_m * 32 + u_m;
        const float sc   = (gt_m == 2) ? NTWOLOG2E : NLOG2E;
        // input-source frag
        {
            float w[8];
            if (wv == 0) {
#pragma unroll
                for (int jj = 0; jj < 8; ++jj) w[jj] = 0.0f;
                if (q == 0) { w[0] = Wih0[rowG * 2]; w[1] = Wih0[rowG * 2 + 1]; }
            } else {
                const float* src = Wih + (wv - 1) * 4096 + rowG * 32 + q * 8;
#pragma unroll
                for (int jj = 0; jj < 8; ++jj) w[jj] = src[jj];
            }
            bf16x8 fr;
#pragma unroll
            for (int jj = 0; jj < 8; ++jj) fr[jj] = (short)f2b(w[jj] * sc);
            afr[0][g] = fr;
        }
        // recurrent frag
        {
            const float* src = Whh + wv * 4096 + rowG * 32 + q * 8;
            bf16x8 fr;
#pragma unroll
            for (int jj = 0; jj < 8; ++jj) fr[jj] = (short)f2b(src[jj] * sc);
            afr[1][g] = fr;
        }
        // bias quad (per D row q*4+r)
        f32x4 c4;
#pragma unroll
        for (int r = 0; r < 4; ++r) {
            const int   u_r  = 8 * q + 2 * (g & 3) + (r & 1);
            const int   gt_r = 2 * (g >> 2) + ((r >> 1) & 1);
            const float scr  = (gt_r == 2) ? NTWOLOG2E : NLOG2E;
            c4[r] = (bih[wv * 128 + gt_r * 32 + u_r] + bhh[wv * 128 + gt_r * 32 + u_r]) * scr;
        }
        cbq[g] = c4;
    }

    // persistent register state: h as next-B-frag, scaled cell state
    bf16x8 hreg[2];     // [tt]; zero = h(0)=0
#pragma unroll
    for (int tt = 0; tt < 2; ++tt) {
        union { unsigned int u[4]; bf16x8 v; } z;
        z.u[0] = 0u; z.u[1] = 0u; z.u[2] = 0u; z.u[3] = 0u;
        hreg[tt] = z.v;
    }
    f32x2 cp2[2][4];    // -2log2e*c for unit pair (8q+2j, +1): [tt][j]
#pragma unroll
    for (int tt = 0; tt < 2; ++tt)
#pragma unroll
        for (int j = 0; j < 4; ++j) cp2[tt][j] = (f32x2){0.0f, 0.0f};

    __syncthreads();

    // packed LSTM epilogue chain for one unit-pair (f32x2)
    auto chain = [&](f32x2 ai, f32x2 af, f32x2 ag, f32x2 ao, f32x2& cpr) -> f32x2 {
        const f32x2 one = {1.0f, 1.0f};
        const f32x2 c2l = {TWOLOG2E, TWOLOG2E};
        const f32x2 n2l = {NTWOLOG2E, NTWOLOG2E};
        f32x2 ei = {fex2(ai.x), fex2(ai.y)};              // e^{-a_i}
        f32x2 ef = {fex2(af.x), fex2(af.y)};              // e^{-a_f}
        f32x2 eg = {fex2(ag.x), fex2(ag.y)};              // e^{-2 a_g}
        f32x2 eo = {fex2(ao.x), fex2(ao.y)};              // e^{-a_o}
        f32x2 apf = one + ef;
        f32x2 p1  = (one + ei) * (one + eg);
        f32x2 Dc  = p1 * apf;
        f32x2 R_  = {frcp(Dc.x), frcp(Dc.y)};
        f32x2 egp = __builtin_elementwise_fma(eg, c2l, n2l);  // -2log2e*(1-eg)
        f32x2 t1  = egp * apf;
        f32x2 t2  = __builtin_elementwise_fma(cpr, p1, t1);
        f32x2 cn  = t2 * R_;                              // scaled cell state
        cpr = cn;
        f32x2 ec  = {fex2(cn.x), fex2(cn.y)};             // e^{-2c}
        f32x2 Dh  = (one + eo) * (one + ec);
        f32x2 Rh  = {frcp(Dh.x), frcp(Dh.y)};
        return (one - ec) * Rh;
    };

    // one timestep for all 32 batch rows (2 x 16-batch tiles)
    auto cell_step = [&](int t, const unsigned int* pin, unsigned int* pout) {
#pragma unroll
        for (int tt = 0; tt < 2; ++tt) {
            // input B-frag: x (wave 0) or layer-below h from LDS (layout-preserving)
            bf16x8 bin;
            if (wv == 0) {
                unsigned int xd = xb[t * 32 + tt * 16 + m];
                union { unsigned int u[4]; bf16x8 v; } au;
                au.u[0] = (q == 0) ? xd : 0u; au.u[1] = 0u; au.u[2] = 0u; au.u[3] = 0u;
                bin = au.v;
            } else {
                bin = *(const bf16x8*)(pin + tt * 256 + lane * 4);
            }
            f32x4 acc[8];
#pragma unroll
            for (int g = 0; g < 8; ++g) {
                acc[g] = __builtin_amdgcn_mfma_f32_16x16x32_bf16(afr[0][g], bin, cbq[g], 0, 0, 0);
                acc[g] = __builtin_amdgcn_mfma_f32_16x16x32_bf16(afr[1][g], hreg[tt], acc[g], 0, 0, 0);
            }
            // epilogue: 4 unit-pair chains; outputs form the next B-frag directly
            union { unsigned int u[4]; bf16x8 v; } hn;
#pragma unroll
            for (int j = 0; j < 4; ++j) {
                f32x2 ai = (f32x2)__builtin_shufflevector(acc[j],     acc[j],     0, 1); // gate i
                f32x2 af = (f32x2)__builtin_shufflevector(acc[j],     acc[j],     2, 3); // gate f
                f32x2 ag = (f32x2)__builtin_shufflevector(acc[4 + j], acc[4 + j], 0, 1); // gate g
                f32x2 ao = (f32x2)__builtin_shufflevector(acc[4 + j], acc[4 + j], 2, 3); // gate o
                f32x2 hh = chain(ai, af, ag, ao, cp2[tt][j]);
                hn.u[j] = pk2(hh.x, hh.y);
            }
            hreg[tt] = hn.v;                                   // register recurrence
            *(bf16x8*)(pout + tt * 256 + lane * 4) = hn.v;     // cross-layer handoff
        }
    };

    for (int S = 0; S < 35; ++S) {
        const int t0 = 2 * (S - wv);          // wave-uniform
        if (t0 >= 0 && t0 <= 62) {
            const int p  = S & 1;
            const int pb = p ^ 1;
            unsigned int*       Lc0 = hb + ((wv * 2 + p ) * 2    ) * 512;  // own layer, cur parity, slot0
            unsigned int*       Lc1 = Lc0 + 512;                            // slot1
            const int           lb  = (wv > 0) ? (wv - 1) : 0;
            const unsigned int* Dp0 = hb + ((lb * 2 + pb) * 2    ) * 512;  // layer below, prev parity, slot0
            const unsigned int* Dp1 = Dp0 + 512;                            // slot1

            cell_step(t0,     Dp0, Lc0);   // t0: input h_{l-1}(t0); recurrent = hreg
            cell_step(t0 + 1, Dp1, Lc1);   // t1: input h_{l-1}(t1); recurrent = hreg (updated)
        }
        __syncthreads();
    }

    // output head: h3(t=63) -> written by wave 3 at S=34 (p=0), slot1
    if (tid < 32) {
        const unsigned int* h3 = hb + ((3 * 2 + 0) * 2 + 1) * 512;
        const int tt = tid >> 4, mm = tid & 15;
        float s = blin[0];
#pragma unroll
        for (int qq = 0; qq < 4; ++qq)
#pragma unroll
            for (int j = 0; j < 4; ++j) {
                unsigned int w2 = h3[tt * 256 + (qq * 16 + mm) * 4 + j];
                const int u0 = 8 * qq + 2 * j;
                s += Wlin[u0]     * b2f((unsigned short)(w2 & 0xffffu));
                s += Wlin[u0 + 1] * b2f((unsigned short)(w2 >> 16));
            }
        out[row0 + tid] = frcp(1.0f + fex2(s * NLOG2E));
    }
}

extern "C" void kernel_launch(void* const* d_in, const int* in_sizes, int n_in,
                              void* d_out, int out_size, void* d_ws, size_t ws_size,
                              hipStream_t stream) {
    const float* x    = (const float*)d_in[0];
    const float* Wih0 = (const float*)d_in[1];
    const float* Wih  = (const float*)d_in[2];
    const float* Whh  = (const float*)d_in[3];
    const float* bih  = (const float*)d_in[4];
    const float* bhh  = (const float*)d_in[5];
    const float* Wlin = (const float*)d_in[6];
    const float* blin = (const float*)d_in[7];
    float* out = (float*)d_out;

    lstm_mfma<<<512, 256, 0, stream>>>(x, Wih0, Wih, Whh, bih, bhh, Wlin, blin, out);
}